// Round 16
// baseline (22.205 us; speedup 1.0000x reference)
//
#include <hip/hip_runtime.h>
#include <hip/hip_fp16.h>
#include <math.h>

// Problem constants: N=2000 politicians, B=2000 bills, D=32, K(order)=3.
#define NN    2000
#define NB    2000
#define DD    32
#define NOCT  16                   // K=128: octs 0-11 data, 12 poly, 13-15 zero
#define TILE  64                   // pol tile; bill macro-tile = 2*TILE = 128
#define GDX   16                   // bill macro-tiles (2048/128)
#define GDY   32                   // pol tiles (2048/64)
#define NPART (GDX * GDY)          // 512 partials

typedef _Float16 half8   __attribute__((ext_vector_type(8)));
typedef _Float16 half4   __attribute__((ext_vector_type(4)));
typedef float    float4v __attribute__((ext_vector_type(4)));

__device__ __forceinline__ float dot4(const float4 a, const float4 b) {
    return fmaf(a.x, b.x, fmaf(a.y, b.y, fmaf(a.z, b.z, a.w * b.w)));
}
__device__ __forceinline__ half4 cvt4(const float x, const float y,
                                      const float z, const float w) {
    half4 h; h[0] = (_Float16)x; h[1] = (_Float16)y;
    h[2] = (_Float16)z; h[3] = (_Float16)w; return h;
}

// r15 structure, macro-tiled: one 64-pol x 128-bill block. W built once per
// 128 bills (build redundancy halved), af fragments reused across both bill
// sub-tiles, single build barrier. fp16 MFMA K=128 -> -dist^2/2, logistic
// epilogue, block partial to ws. 2 dispatches, no atomics, no fences.
__global__ __launch_bounds__(256, 2) void pol2vec_main(
    const int*   __restrict__ events,   // [N,B] 0/1
    const float* __restrict__ tarr,     // [B]
    const float* __restrict__ beta,     // [B]
    const float* __restrict__ gamma,    // [N]
    const float* __restrict__ zb,       // [B,D]
    const float* __restrict__ zp,       // [K,N,D]
    float*       __restrict__ partials) // [NPART]
{
    __shared__ _Float16 sW[NOCT * TILE * 8];        // 16KB
    __shared__ _Float16 sZ[2][NOCT * TILE * 8];     // 32KB (two bill sub-tiles)
    __shared__ float    s_red[4];

    const int tid  = threadIdx.x;
    const int lane = tid & 63;
    const int w    = tid >> 6;
    const int b0   = blockIdx.x * (2 * TILE);       // 128-bill macro-tile base
    const int n0   = blockIdx.y * TILE;             // 64-pol tile base
    const int wr   = (w >> 1) * 32;
    const int wc   = (w & 1) * 32;
    const int l15  = lane & 15;
    const int l4   = lane >> 4;

    // ---- Events gather first: 32 independent loads, latency hides under build.
    unsigned evb[2] = {0u, 0u}, vb[2] = {0u, 0u};
#pragma unroll
    for (int tau = 0; tau < 2; ++tau)
#pragma unroll
    for (int nr = 0; nr < 2; ++nr)
#pragma unroll
    for (int bc = 0; bc < 2; ++bc)
#pragma unroll
    for (int r = 0; r < 4; ++r) {
        const int ng = n0 + wr + 16 * nr + l4 * 4 + r;
        const int bg = b0 + tau * TILE + wc + 16 * bc + l15;
        const bool v = (ng < NN) && (bg < NB);
        const size_t idx = v ? ((size_t)ng * NB + bg) : 0;
        const unsigned bit = 1u << (nr * 8 + bc * 4 + r);
        if (v) vb[tau] |= bit;
        if (v && events[idx]) evb[tau] |= bit;
    }

    // ---- Zero octets 13-15 (all three operand tiles).
    if (tid < 3 * TILE) {
        const half8 zz = {};
        *(half8*)(sW    + ((size_t)(13 * TILE + tid)) * 8) = zz;
        *(half8*)(sZ[0] + ((size_t)(13 * TILE + tid)) * 8) = zz;
        *(half8*)(sZ[1] + ((size_t)(13 * TILE + tid)) * 8) = zz;
    }

    const int row = tid >> 3;          // 0..31
    const int q   = tid & 7;           // float4 index within 32-dim row
    const int hs  = (q & 1) * 4;       // half4 slot within octet row

    // ---- W side (once per block): 2 passes x 3 coalesced float4 loads; same
    // registers feed fragment writes AND the 6 coefficient dots.
#pragma unroll
    for (int p = 0; p < 2; ++p) {
        const int nl = 32 * p + row;
        const int n  = n0 + nl;
        float4 a4 = {0.f,0.f,0.f,0.f}, b4 = {0.f,0.f,0.f,0.f}, c4 = {0.f,0.f,0.f,0.f};
        if (n < NN) {
            a4 = ((const float4*)(zp + (size_t)n * DD))[q];
            b4 = ((const float4*)(zp + ((size_t)NN + n) * DD))[q];
            c4 = ((const float4*)(zp + ((size_t)2 * NN + n) * DD))[q];
        }
        *(half4*)(sW + ((size_t)((0 + (q >> 1)) * TILE + nl)) * 8 + hs) =
            cvt4(a4.x, a4.y, a4.z, a4.w);
        *(half4*)(sW + ((size_t)((4 + (q >> 1)) * TILE + nl)) * 8 + hs) =
            cvt4(b4.x, b4.y, b4.z, b4.w);
        *(half4*)(sW + ((size_t)((8 + (q >> 1)) * TILE + nl)) * 8 + hs) =
            cvt4(c4.x, c4.y, c4.z, c4.w);

        float paa = dot4(a4, a4), pab = dot4(a4, b4), pac = dot4(a4, c4);
        float pbb = dot4(b4, b4), pbc = dot4(b4, c4), pcc = dot4(c4, c4);
#pragma unroll
        for (int off = 1; off < 8; off <<= 1) {
            paa += __shfl_xor(paa, off); pab += __shfl_xor(pab, off);
            pac += __shfl_xor(pac, off); pbb += __shfl_xor(pbb, off);
            pbc += __shfl_xor(pbc, off); pcc += __shfl_xor(pcc, off);
        }
        if (q == 0) {
            half8 hv = {};
            hv[0] = (_Float16)paa;            // |A|^2
            hv[1] = (_Float16)(2.f * pab);    // 2 A.B
            hv[2] = (_Float16)(pbb + pac);    // |B|^2 + A.C
            hv[3] = (_Float16)pbc;            // B.C
            hv[4] = (_Float16)(0.25f * pcc);  // |C|^2/4
            hv[5] = (_Float16)1.f;
            *(half8*)(sW + ((size_t)(12 * TILE + nl)) * 8) = hv;
        }
    }

    // ---- Zf side: 4 passes cover 128 bill rows across both sub-tiles.
#pragma unroll
    for (int p = 0; p < 4; ++p) {
        const int bl  = 32 * p + row;      // 0..127
        const int tau = bl >> 6;
        const int r64 = bl & 63;
        const int b   = b0 + bl;
        float4 z4 = {0.f,0.f,0.f,0.f};
        float t = 0.f;
        if (b < NB) {
            z4 = ((const float4*)(zb + (size_t)b * DD))[q];
            t  = tarr[b];
        }
        const float th = 0.5f * t * t;
        _Float16* base = sZ[tau];
        *(half4*)(base + ((size_t)((0 + (q >> 1)) * TILE + r64)) * 8 + hs) =
            cvt4(z4.x, z4.y, z4.z, z4.w);
        *(half4*)(base + ((size_t)((4 + (q >> 1)) * TILE + r64)) * 8 + hs) =
            cvt4(t * z4.x, t * z4.y, t * z4.z, t * z4.w);
        *(half4*)(base + ((size_t)((8 + (q >> 1)) * TILE + r64)) * 8 + hs) =
            cvt4(th * z4.x, th * z4.y, th * z4.z, th * z4.w);

        float pz2 = dot4(z4, z4);
#pragma unroll
        for (int off = 1; off < 8; off <<= 1) pz2 += __shfl_xor(pz2, off);
        if (q == 0) {
            const float t2 = t * t;
            half8 hv = {};
            hv[0] = (_Float16)(-0.5f);
            hv[1] = (_Float16)(-0.5f * t);
            hv[2] = (_Float16)(-0.5f * t2);
            hv[3] = (_Float16)(-0.5f * t2 * t);
            hv[4] = (_Float16)(-0.5f * t2 * t2);
            hv[5] = (_Float16)(-0.5f * pz2);
            *(half8*)(base + ((size_t)(12 * TILE + r64)) * 8) = hv;
        }
    }
    __syncthreads();

    // ---- af fragments loaded ONCE, reused for both bill sub-tiles.
    half8 af[2][4];
#pragma unroll
    for (int ks = 0; ks < 4; ++ks) {
        const int oct = 4 * ks + l4;
#pragma unroll
        for (int h = 0; h < 2; ++h)
            af[h][ks] = *(const half8*)(sW + ((size_t)oct * TILE + wr + 16 * h + l15) * 8);
    }

    float accs = 0.f;
#pragma unroll
    for (int tau = 0; tau < 2; ++tau) {
        half8 bf[2][4];
#pragma unroll
        for (int ks = 0; ks < 4; ++ks) {
            const int oct = 4 * ks + l4;
#pragma unroll
            for (int h = 0; h < 2; ++h)
                bf[h][ks] = *(const half8*)(sZ[tau] + ((size_t)oct * TILE + wc + 16 * h + l15) * 8);
        }

        float4v acc[2][2] = {};
#pragma unroll
        for (int nr = 0; nr < 2; ++nr)
#pragma unroll
        for (int bc = 0; bc < 2; ++bc)
#pragma unroll
        for (int ks = 0; ks < 4; ++ks)
            acc[nr][bc] = __builtin_amdgcn_mfma_f32_16x16x32_f16(
                af[nr][ks], bf[bc][ks], acc[nr][bc], 0, 0, 0);

        // Epilogue: acc = -dist^2/2;  L = gamma + beta - dist.
#pragma unroll
        for (int bc = 0; bc < 2; ++bc) {
            const int bg = b0 + tau * TILE + wc + 16 * bc + l15;
            const float be = beta[bg < NB ? bg : 0];
#pragma unroll
            for (int nr = 0; nr < 2; ++nr) {
#pragma unroll
                for (int r = 0; r < 4; ++r) {
                    const int ng = n0 + wr + 16 * nr + l4 * 4 + r;
                    const float g = gamma[ng < NN ? ng : 0];
                    const float d2 = fmaxf(-2.f * acc[nr][bc][r], 0.f);
                    const float L  = g + be - sqrtf(d2);
                    const unsigned bit = 1u << (nr * 8 + bc * 4 + r);
                    const float sgn = (evb[tau] & bit) ? 1.f : -1.f;
                    const float s   = sgn * L;
                    const float term = fmaxf(-s, 0.f) + __logf(1.f + __expf(-fabsf(s)));
                    accs += (vb[tau] & bit) ? term : 0.f;
                }
            }
        }
    }

    // ---- Block partial (no atomics, no fences).
#pragma unroll
    for (int o = 32; o > 0; o >>= 1) accs += __shfl_down(accs, o, 64);
    if (lane == 0) s_red[w] = accs;
    __syncthreads();
    if (tid == 0)
        partials[blockIdx.y * GDX + blockIdx.x] =
            (s_red[0] + s_red[1]) + (s_red[2] + s_red[3]);
}

// Reduce: 512 partials -> d_out[0] (overwrite; poison-proof).
__global__ __launch_bounds__(256) void pol2vec_reduce(
    const float2* __restrict__ p2, float* __restrict__ out)
{
    __shared__ float s_red[4];
    const int tid = threadIdx.x;
    const float2 v = p2[tid];                 // 256 threads x float2 = 512
    float s = v.x + v.y;
#pragma unroll
    for (int o = 32; o > 0; o >>= 1) s += __shfl_down(s, o, 64);
    if ((tid & 63) == 0) s_red[tid >> 6] = s;
    __syncthreads();
    if (tid == 0) out[0] = (s_red[0] + s_red[1]) + (s_red[2] + s_red[3]);
}

extern "C" void kernel_launch(void* const* d_in, const int* in_sizes, int n_in,
                              void* d_out, int out_size, void* d_ws, size_t ws_size,
                              hipStream_t stream) {
    const int*   events = (const int*)d_in[0];    // [N,B]
    const float* tarr   = (const float*)d_in[1];  // [B]
    const float* beta   = (const float*)d_in[2];  // [B]
    const float* gamma  = (const float*)d_in[3];  // [N]
    const float* zb     = (const float*)d_in[4];  // [B,D]
    const float* zp     = (const float*)d_in[5];  // [K,N,D]
    float* out = (float*)d_out;

    float* parts = (float*)d_ws;                  // [NPART], overwritten

    dim3 grid(GDX, GDY);
    pol2vec_main<<<grid, 256, 0, stream>>>(events, tarr, beta, gamma, zb, zp,
                                           parts);
    pol2vec_reduce<<<1, 256, 0, stream>>>((const float2*)parts, out);
}

// Round 17
// 20.514 us; speedup vs baseline: 1.0824x; 1.0824x over previous
//
#include <hip/hip_runtime.h>
#include <hip/hip_fp16.h>
#include <math.h>

// Problem constants: N=2000 politicians, B=2000 bills, D=32, K(order)=3.
#define NN    2000
#define NB    2000
#define DD    32
#define NOCT  16                   // K=128: octs 0-11 data, 12 poly, 13-15 zero
#define TILE  64                   // block tile: 64 pols x 64 bills
#define GDIM  32                   // 2048/64
#define NPART (GDIM * GDIM)        // 1024 partials

typedef _Float16 half8   __attribute__((ext_vector_type(8)));
typedef _Float16 half4   __attribute__((ext_vector_type(4)));
typedef float    float4v __attribute__((ext_vector_type(4)));

__device__ __forceinline__ float dot4(const float4 a, const float4 b) {
    return fmaf(a.x, b.x, fmaf(a.y, b.y, fmaf(a.z, b.z, a.w * b.w)));
}
__device__ __forceinline__ half4 cvt4(const float x, const float y,
                                      const float z, const float w) {
    half4 h; h[0] = (_Float16)x; h[1] = (_Float16)y;
    h[2] = (_Float16)z; h[3] = (_Float16)w; return h;
}

// Best measured structure (r15, 20.4us): fused coalesced in-block build
// (8 threads/row -> every global access line-coalesced; zp/zb read once),
// fp16 MFMA K=128 -> -dist^2/2 directly, logistic epilogue, block partial
// to ws + tiny reduce. 2 dispatches, no atomics, no fences, no memset.
__global__ __launch_bounds__(256, 4) void pol2vec_main(
    const int*   __restrict__ events,   // [N,B] 0/1
    const float* __restrict__ tarr,     // [B]
    const float* __restrict__ beta,     // [B]
    const float* __restrict__ gamma,    // [N]
    const float* __restrict__ zb,       // [B,D]
    const float* __restrict__ zp,       // [K,N,D]
    float*       __restrict__ partials) // [NPART]
{
    __shared__ _Float16 sW[NOCT * TILE * 8];   // 16KB
    __shared__ _Float16 sZ[NOCT * TILE * 8];   // 16KB
    __shared__ float    s_red[4];

    const int tid  = threadIdx.x;
    const int lane = tid & 63;
    const int w    = tid >> 6;
    const int b0   = blockIdx.x * TILE;
    const int n0   = blockIdx.y * TILE;
    const int wr   = (w >> 1) * 32;
    const int wc   = (w & 1) * 32;
    const int l15  = lane & 15;
    const int l4   = lane >> 4;

    // ---- Events gather first: 16 independent loads, latency hides under build.
    unsigned evb = 0u, vb = 0u;
#pragma unroll
    for (int nr = 0; nr < 2; ++nr)
#pragma unroll
    for (int bc = 0; bc < 2; ++bc)
#pragma unroll
    for (int r = 0; r < 4; ++r) {
        const int ng = n0 + wr + 16 * nr + l4 * 4 + r;
        const int bg = b0 + wc + 16 * bc + l15;
        const bool v = (ng < NN) && (bg < NB);
        const size_t idx = v ? ((size_t)ng * NB + bg) : 0;
        const unsigned bit = 1u << (nr * 8 + bc * 4 + r);
        if (v) vb |= bit;
        if (v && events[idx]) evb |= bit;
    }

    // ---- Zero octets 13-15 (both operands).
    if (tid < 3 * TILE) {
        const half8 zz = {};
        *(half8*)(sW + ((size_t)(13 * TILE + tid)) * 8) = zz;
        *(half8*)(sZ + ((size_t)(13 * TILE + tid)) * 8) = zz;
    }

    const int row = tid >> 3;          // 0..31 (row within half-tile)
    const int q   = tid & 7;           // float4 index within 32-dim row
    const int hs  = (q & 1) * 4;       // half4 slot within octet row

    // ---- W side: 2 passes x 3 coalesced float4 loads; same registers feed
    // fragment writes AND the 6 coefficient dots (zp read exactly once).
#pragma unroll
    for (int p = 0; p < 2; ++p) {
        const int nl = 32 * p + row;
        const int n  = n0 + nl;
        float4 a4 = {0.f,0.f,0.f,0.f}, b4 = {0.f,0.f,0.f,0.f}, c4 = {0.f,0.f,0.f,0.f};
        if (n < NN) {
            a4 = ((const float4*)(zp + (size_t)n * DD))[q];
            b4 = ((const float4*)(zp + ((size_t)NN + n) * DD))[q];
            c4 = ((const float4*)(zp + ((size_t)2 * NN + n) * DD))[q];
        }
        *(half4*)(sW + ((size_t)((0 + (q >> 1)) * TILE + nl)) * 8 + hs) =
            cvt4(a4.x, a4.y, a4.z, a4.w);
        *(half4*)(sW + ((size_t)((4 + (q >> 1)) * TILE + nl)) * 8 + hs) =
            cvt4(b4.x, b4.y, b4.z, b4.w);
        *(half4*)(sW + ((size_t)((8 + (q >> 1)) * TILE + nl)) * 8 + hs) =
            cvt4(c4.x, c4.y, c4.z, c4.w);

        float paa = dot4(a4, a4), pab = dot4(a4, b4), pac = dot4(a4, c4);
        float pbb = dot4(b4, b4), pbc = dot4(b4, c4), pcc = dot4(c4, c4);
#pragma unroll
        for (int off = 1; off < 8; off <<= 1) {
            paa += __shfl_xor(paa, off); pab += __shfl_xor(pab, off);
            pac += __shfl_xor(pac, off); pbb += __shfl_xor(pbb, off);
            pbc += __shfl_xor(pbc, off); pcc += __shfl_xor(pcc, off);
        }
        if (q == 0) {
            half8 hv = {};
            hv[0] = (_Float16)paa;            // |A|^2
            hv[1] = (_Float16)(2.f * pab);    // 2 A.B
            hv[2] = (_Float16)(pbb + pac);    // |B|^2 + A.C
            hv[3] = (_Float16)pbc;            // B.C
            hv[4] = (_Float16)(0.25f * pcc);  // |C|^2/4
            hv[5] = (_Float16)1.f;
            *(half8*)(sW + ((size_t)(12 * TILE + nl)) * 8) = hv;
        }
    }

    // ---- Zf side: z, t*z, (t^2/2)*z octets + poly row (z2 via shuffles).
#pragma unroll
    for (int p = 0; p < 2; ++p) {
        const int bl = 32 * p + row;
        const int b  = b0 + bl;
        float4 z4 = {0.f,0.f,0.f,0.f};
        float t = 0.f;
        if (b < NB) {
            z4 = ((const float4*)(zb + (size_t)b * DD))[q];
            t  = tarr[b];
        }
        const float th = 0.5f * t * t;
        *(half4*)(sZ + ((size_t)((0 + (q >> 1)) * TILE + bl)) * 8 + hs) =
            cvt4(z4.x, z4.y, z4.z, z4.w);
        *(half4*)(sZ + ((size_t)((4 + (q >> 1)) * TILE + bl)) * 8 + hs) =
            cvt4(t * z4.x, t * z4.y, t * z4.z, t * z4.w);
        *(half4*)(sZ + ((size_t)((8 + (q >> 1)) * TILE + bl)) * 8 + hs) =
            cvt4(th * z4.x, th * z4.y, th * z4.z, th * z4.w);

        float pz2 = dot4(z4, z4);
#pragma unroll
        for (int off = 1; off < 8; off <<= 1) pz2 += __shfl_xor(pz2, off);
        if (q == 0) {
            const float t2 = t * t;
            half8 hv = {};
            hv[0] = (_Float16)(-0.5f);
            hv[1] = (_Float16)(-0.5f * t);
            hv[2] = (_Float16)(-0.5f * t2);
            hv[3] = (_Float16)(-0.5f * t2 * t);
            hv[4] = (_Float16)(-0.5f * t2 * t2);
            hv[5] = (_Float16)(-0.5f * pz2);
            *(half8*)(sZ + ((size_t)(12 * TILE + bl)) * 8) = hv;
        }
    }
    __syncthreads();

    // ---- Fragment loads from LDS (K=128: 4 K-steps). Proven layout.
    half8 af[2][4], bf[2][4];
#pragma unroll
    for (int ks = 0; ks < 4; ++ks) {
        const int oct = 4 * ks + l4;
#pragma unroll
        for (int h = 0; h < 2; ++h) {
            af[h][ks] = *(const half8*)(sW + ((size_t)oct * TILE + wr + 16 * h + l15) * 8);
            bf[h][ks] = *(const half8*)(sZ + ((size_t)oct * TILE + wc + 16 * h + l15) * 8);
        }
    }

    float4v acc[2][2] = {};
#pragma unroll
    for (int nr = 0; nr < 2; ++nr)
#pragma unroll
    for (int bc = 0; bc < 2; ++bc)
#pragma unroll
    for (int ks = 0; ks < 4; ++ks)
        acc[nr][bc] = __builtin_amdgcn_mfma_f32_16x16x32_f16(
            af[nr][ks], bf[bc][ks], acc[nr][bc], 0, 0, 0);

    // ---- Epilogue: acc = -dist^2/2;  L = gamma + beta - dist.
    float accs = 0.f;
#pragma unroll
    for (int bc = 0; bc < 2; ++bc) {
        const int bg = b0 + wc + 16 * bc + l15;
        const float be = beta[bg < NB ? bg : 0];
#pragma unroll
        for (int nr = 0; nr < 2; ++nr) {
#pragma unroll
            for (int r = 0; r < 4; ++r) {
                const int ng = n0 + wr + 16 * nr + l4 * 4 + r;
                const float g = gamma[ng < NN ? ng : 0];
                const float d2 = fmaxf(-2.f * acc[nr][bc][r], 0.f);
                const float L  = g + be - sqrtf(d2);
                const unsigned bit = 1u << (nr * 8 + bc * 4 + r);
                const float sgn = (evb & bit) ? 1.f : -1.f;
                const float s   = sgn * L;
                const float term = fmaxf(-s, 0.f) + __logf(1.f + __expf(-fabsf(s)));
                accs += (vb & bit) ? term : 0.f;
            }
        }
    }

    // ---- Block partial (no atomics, no fences).
#pragma unroll
    for (int o = 32; o > 0; o >>= 1) accs += __shfl_down(accs, o, 64);
    if (lane == 0) s_red[w] = accs;
    __syncthreads();
    if (tid == 0)
        partials[blockIdx.y * GDIM + blockIdx.x] =
            (s_red[0] + s_red[1]) + (s_red[2] + s_red[3]);
}

// Reduce: 1024 partials -> d_out[0] (overwrite; poison-proof).
__global__ __launch_bounds__(256) void pol2vec_reduce(
    const float4* __restrict__ p4, float* __restrict__ out)
{
    __shared__ float s_red[4];
    const int tid = threadIdx.x;
    const float4 v = p4[tid];                 // 256 threads x float4 = 1024
    float s = (v.x + v.y) + (v.z + v.w);
#pragma unroll
    for (int o = 32; o > 0; o >>= 1) s += __shfl_down(s, o, 64);
    if ((tid & 63) == 0) s_red[tid >> 6] = s;
    __syncthreads();
    if (tid == 0) out[0] = (s_red[0] + s_red[1]) + (s_red[2] + s_red[3]);
}

extern "C" void kernel_launch(void* const* d_in, const int* in_sizes, int n_in,
                              void* d_out, int out_size, void* d_ws, size_t ws_size,
                              hipStream_t stream) {
    const int*   events = (const int*)d_in[0];    // [N,B]
    const float* tarr   = (const float*)d_in[1];  // [B]
    const float* beta   = (const float*)d_in[2];  // [B]
    const float* gamma  = (const float*)d_in[3];  // [N]
    const float* zb     = (const float*)d_in[4];  // [B,D]
    const float* zp     = (const float*)d_in[5];  // [K,N,D]
    float* out = (float*)d_out;

    float* parts = (float*)d_ws;                  // [NPART], overwritten

    dim3 grid(GDIM, GDIM);
    pol2vec_main<<<grid, 256, 0, stream>>>(events, tarr, beta, gamma, zb, zp,
                                           parts);
    pol2vec_reduce<<<1, 256, 0, stream>>>((const float4*)parts, out);
}